// Round 25
// baseline (126.006 us; speedup 1.0000x reference)
//
#include <hip/hip_runtime.h>
#include <hip/hip_bf16.h>

constexpr int NN = 4096;   // nodes
constexpr int CC = 64;     // channels
constexpr int NH = 4;      // heads
constexpr int DH = 16;     // head dim
constexpr int KSPLIT = 4;  // attention K-dimension split (exact partial sums)
constexpr int KVB = 128;   // K/V chunk size (columns) per staging round

typedef _Float16 f16x4 __attribute__((ext_vector_type(4)));
typedef _Float16 f16x8 __attribute__((ext_vector_type(8)));
typedef float f32x4 __attribute__((ext_vector_type(4)));

#define QSCALE 0.36067376022224085f  // 0.25 * log2(e)
#define L2E2   2.8853900817779268f   // 2 * log2(e), for tanh

#if defined(__has_builtin)
#if __has_builtin(__builtin_amdgcn_exp2f)
#define FAST_EXP2(x) __builtin_amdgcn_exp2f(x)
#endif
#if __has_builtin(__builtin_amdgcn_rcpf)
#define FAST_RCP(x) __builtin_amdgcn_rcpf(x)
#endif
#endif
#ifndef FAST_EXP2
#define FAST_EXP2(x) exp2f(x)
#endif
#ifndef FAST_RCP
#define FAST_RCP(x) (1.0f / (x))
#endif

__device__ __forceinline__ float fast_tanh(float x) {
  const float t = FAST_EXP2(x * L2E2);
  return fmaf(-2.f, FAST_RCP(t + 1.f), 1.f);
}

// ---------------------------------------------------------------------------
// Fused project + QKV (R24 verbatim).
__global__ __launch_bounds__(256) void proj_qkv_k(
    const float* __restrict__ inp, const float* __restrict__ Wp,
    const float* __restrict__ bp, const float* __restrict__ Wqkv,
    const float* __restrict__ bqkv, float* __restrict__ xout,
    _Float16* __restrict__ f16b)
{
  __shared__ __align__(16) float As[64][68];
  __shared__ __align__(16) float Xs[64][68];
  __shared__ __align__(16) float W2s[64][196];

  const int tid = threadIdx.x;
  const int rowbase = blockIdx.x * 64;
  const int r4 = (tid & 15) * 4;
  const int cg = (tid >> 4) * 4;
  const int cg2 = (tid >> 4) * 12;

  float acc[4][4];
  #pragma unroll
  for (int i = 0; i < 4; ++i)
    #pragma unroll
    for (int j = 0; j < 4; ++j) acc[i][j] = 0.f;

  for (int k0 = 0; k0 < 128; k0 += 64) {
    if (k0) __syncthreads();
    #pragma unroll
    for (int i = 0; i < 16; ++i) {
      int idx = tid + i * 256;
      int c2 = idx >> 6, kk = idx & 63;
      Xs[kk][c2] = Wp[(size_t)c2 * 128 + k0 + kk];
    }
    #pragma unroll
    for (int i = 0; i < 16; ++i) {
      int idx = tid + i * 256;
      int r = idx >> 6, kk = idx & 63;
      As[kk][r] = inp[(size_t)(rowbase + r) * 128 + k0 + kk];
    }
    __syncthreads();
    #pragma unroll 4
    for (int kk = 0; kk < 64; ++kk) {
      const float4 a = *(const float4*)&As[kk][r4];
      const float4 w4 = *(const float4*)&Xs[kk][cg];
      const float av[4] = {a.x, a.y, a.z, a.w};
      const float wv[4] = {w4.x, w4.y, w4.z, w4.w};
      #pragma unroll
      for (int ri = 0; ri < 4; ++ri)
        #pragma unroll
        for (int ci = 0; ci < 4; ++ci)
          acc[ri][ci] = fmaf(av[ri], wv[ci], acc[ri][ci]);
    }
  }

  float xv[4][4];
  #pragma unroll
  for (int ri = 0; ri < 4; ++ri)
    #pragma unroll
    for (int j = 0; j < 4; ++j) {
      xv[ri][j] = acc[ri][j] + bp[cg + j];
      xout[(size_t)(rowbase + r4 + ri) * CC + cg + j] = xv[ri][j];
    }

  __syncthreads();
  #pragma unroll
  for (int ri = 0; ri < 4; ++ri)
    #pragma unroll
    for (int j = 0; j < 4; ++j)
      Xs[cg + j][r4 + ri] = xv[ri][j];
  #pragma unroll
  for (int i = 0; i < 48; ++i) {
    int idx = tid + i * 256;
    int c2 = idx >> 6, kk = idx & 63;
    W2s[kk][c2] = Wqkv[(size_t)c2 * 64 + kk];
  }
  __syncthreads();

  float acc2[4][12];
  #pragma unroll
  for (int i = 0; i < 4; ++i)
    #pragma unroll
    for (int j = 0; j < 12; ++j) acc2[i][j] = 0.f;

  #pragma unroll 4
  for (int kk = 0; kk < 64; ++kk) {
    const float4 a = *(const float4*)&Xs[kk][r4];
    const float av[4] = {a.x, a.y, a.z, a.w};
    #pragma unroll
    for (int cj = 0; cj < 3; ++cj) {
      const float4 w4 = *(const float4*)&W2s[kk][cg2 + cj * 4];
      const float wv[4] = {w4.x, w4.y, w4.z, w4.w};
      #pragma unroll
      for (int ri = 0; ri < 4; ++ri)
        #pragma unroll
        for (int ci = 0; ci < 4; ++ci)
          acc2[ri][cj * 4 + ci] = fmaf(av[ri], wv[ci], acc2[ri][cj * 4 + ci]);
    }
  }

  #pragma unroll
  for (int ri = 0; ri < 4; ++ri) {
    const int row = rowbase + r4 + ri;
    const int n = row & (NN - 1);
    const int bq = (row >> 12) * NH;
    #pragma unroll
    for (int j = 0; j < 12; ++j) {
      float v = acc2[ri][j] + bqkv[cg2 + j];
      const int c2 = cg2 + j;
      const int which = c2 >> 6;         // 0=q 1=k 2=v
      const int hc = c2 & 63;
      const int bh = bq + (hc >> 4);
      const int d = hc & 15;
      if (which == 0) v *= QSCALE;
      if (which < 2)
        f16b[(size_t)which * 1048576 + ((size_t)bh * NN + n) * DH + d] = (_Float16)v;
      else
        f16b[2097152 + ((size_t)bh * DH + d) * NN + n] = (_Float16)v;
    }
  }
}

// ---------------------------------------------------------------------------
// MFMA flash attention, K-split x4, f16 partials, KVB=128 chunks (16 barriers
// per block instead of 32), single LDS buffer + register prefetch (f16x8).
__global__ __launch_bounds__(256, 6) void attn_k(
    const _Float16* __restrict__ qb, const _Float16* __restrict__ kb,
    const _Float16* __restrict__ vtb, _Float16* __restrict__ po,
    _Float16* __restrict__ rs)
{
  __shared__ _Float16 Kl[KVB][20];      // [k-row][d], row 40B
  __shared__ _Float16 Vl[16][KVB + 8];  // [d][k-col], row 272B

  const int bid = blockIdx.x;
  const int xcd = bid & 7;
  const int rest = bid >> 3;
  const int bh = 2 * xcd + (rest & 1);
  const int ks = (rest >> 1) & 3;
  const int n0 = (rest >> 3) * 128;
  const int tid = threadIdx.x;
  const int w = tid >> 6;
  const int l = tid & 63;
  const int g = l >> 4, i = l & 15;
  const int qbase = n0 + w * 32;
  const int kbeg = ks * (NN / KSPLIT);

  const _Float16* __restrict__ qhp = qb + (size_t)bh * NN * DH;
  const _Float16* __restrict__ khp = kb + (size_t)bh * NN * DH;
  const _Float16* __restrict__ vhp = vtb + (size_t)bh * DH * NN;

  const f16x4 qfA = *(const f16x4*)(qhp + (size_t)(qbase + i) * DH + 4 * g);
  const f16x4 qfB = *(const f16x4*)(qhp + (size_t)(qbase + 16 + i) * DH + 4 * g);

  f32x4 oA = {0.f, 0.f, 0.f, 0.f}, oB = {0.f, 0.f, 0.f, 0.f};
  const f32x4 zz = {0.f, 0.f, 0.f, 0.f};
  float rsA = 0.f, rsB = 0.f;

  // staging maps: one 16B K load + one 16B V load per thread per chunk
  const int sr = tid >> 1, sh = (tid & 1) * 8;    // K: row 0..127, half-row
  const int sd = tid >> 4, sc = (tid & 15) * 8;   // V: d-row, col8

  f16x8 kr = *(const f16x8*)(khp + (size_t)(kbeg + sr) * DH + sh);
  f16x8 vr = *(const f16x8*)(vhp + (size_t)sd * NN + kbeg + sc);

  constexpr int NCH = (NN / KSPLIT) / KVB;  // 8
  for (int c = 0; c < NCH; ++c) {
    *(f16x8*)&Kl[sr][sh] = kr;
    *(f16x8*)&Vl[sd][sc] = vr;
    __syncthreads();
    if (c + 1 < NCH) {  // issue next chunk's loads; waited on next LDS write
      const int nx = kbeg + (c + 1) * KVB;
      kr = *(const f16x8*)(khp + (size_t)(nx + sr) * DH + sh);
      vr = *(const f16x8*)(vhp + (size_t)sd * NN + nx + sc);
    }

    #pragma unroll
    for (int kk = 0; kk < KVB; kk += 16) {
      const f16x4 kf = *(const f16x4*)&Kl[kk + i][4 * g];
      const f16x4 vf = *(const f16x4*)&Vl[i][kk + 4 * g];
      f32x4 sA = __builtin_amdgcn_mfma_f32_16x16x16f16(kf, qfA, zz, 0, 0, 0);
      f32x4 sB = __builtin_amdgcn_mfma_f32_16x16x16f16(kf, qfB, zz, 0, 0, 0);
      const float a0 = FAST_EXP2(sA[0]), a1 = FAST_EXP2(sA[1]),
                  a2 = FAST_EXP2(sA[2]), a3 = FAST_EXP2(sA[3]);
      const float b0 = FAST_EXP2(sB[0]), b1 = FAST_EXP2(sB[1]),
                  b2 = FAST_EXP2(sB[2]), b3 = FAST_EXP2(sB[3]);
      rsA += (a0 + a1) + (a2 + a3);
      rsB += (b0 + b1) + (b2 + b3);
      const auto alo = __builtin_amdgcn_cvt_pkrtz(a0, a1);
      const auto ahi = __builtin_amdgcn_cvt_pkrtz(a2, a3);
      const auto blo = __builtin_amdgcn_cvt_pkrtz(b0, b1);
      const auto bhi = __builtin_amdgcn_cvt_pkrtz(b2, b3);
      f16x4 pA, pB;
      pA[0] = (_Float16)alo[0]; pA[1] = (_Float16)alo[1];
      pA[2] = (_Float16)ahi[0]; pA[3] = (_Float16)ahi[1];
      pB[0] = (_Float16)blo[0]; pB[1] = (_Float16)blo[1];
      pB[2] = (_Float16)bhi[0]; pB[3] = (_Float16)bhi[1];
      oA = __builtin_amdgcn_mfma_f32_16x16x16f16(pA, vf, oA, 0, 0, 0);
      oB = __builtin_amdgcn_mfma_f32_16x16x16f16(pB, vf, oB, 0, 0, 0);
    }
    __syncthreads();
  }

  rsA += __shfl_xor(rsA, 16); rsA += __shfl_xor(rsA, 32);
  rsB += __shfl_xor(rsB, 16); rsB += __shfl_xor(rsB, 32);

  _Float16* __restrict__ pob = po + (size_t)(ks * 16 + bh) * NN * DH;
  #pragma unroll
  for (int r = 0; r < 4; ++r) {
    const int ql = 4 * g + r;
    pob[(size_t)(qbase + ql) * DH + i] = (_Float16)oA[r];
    pob[(size_t)(qbase + 16 + ql) * DH + i] = (_Float16)oB[r];
  }
  if (g == 0) {
    _Float16* __restrict__ rsb = rs + (size_t)(ks * 16 + bh) * NN;
    rsb[qbase + i] = (_Float16)rsA;
    rsb[qbase + 16 + i] = (_Float16)rsB;
  }
}

// ---------------------------------------------------------------------------
// Wo GEMM + K-split reduce + residual + BN2 partials (R24 verbatim).
__global__ __launch_bounds__(256) void wo_red_k(
    const _Float16* __restrict__ po, const _Float16* __restrict__ rs,
    const float* __restrict__ Wo, const float* __restrict__ bo,
    const float* __restrict__ xin, float* __restrict__ out,
    float* __restrict__ s2sum, float* __restrict__ s2sq)
{
  __shared__ __align__(16) float As[64][36];
  __shared__ __align__(16) float Ws[64][68];
  __shared__ float Linv[32][4];

  const int tid = threadIdx.x;
  const int rowbase = blockIdx.x * 32;
  const int r2 = (tid & 15) * 2;
  const int cg = (tid >> 4) * 4;

  if (tid < 128) {
    const int r = tid & 31, hb = tid >> 5;
    const int row = rowbase + r;
    const int bh = (row >> 12) * NH + hb;
    const int n = row & (NN - 1);
    const size_t rb = (size_t)bh * NN + n;
    const float s = (float)rs[rb] + (float)rs[rb + 65536] +
                    (float)rs[rb + 131072] + (float)rs[rb + 196608];
    Linv[r][hb] = 1.f / s;
  }
  #pragma unroll
  for (int i = 0; i < 16; ++i) {
    int idx = tid + i * 256;
    int c2 = idx >> 6, kk = idx & 63;
    Ws[kk][c2] = Wo[(size_t)c2 * 64 + kk];
  }
  __syncthreads();
  #pragma unroll
  for (int i = 0; i < 8; ++i) {
    int idx = tid + i * 256;
    int r = idx >> 6, kk = idx & 63;
    const int row = rowbase + r;
    const int bh = (row >> 12) * NH + (kk >> 4);
    const int n = row & (NN - 1);
    const int d = kk & 15;
    const size_t base = (((size_t)bh * NN + n) * DH) + d;
    const float v = (float)po[base] + (float)po[base + 1048576] +
                    (float)po[base + 2097152] + (float)po[base + 3145728];
    As[kk][r] = v * Linv[r][kk >> 4];
  }
  __syncthreads();

  float acc[2][4];
  #pragma unroll
  for (int i = 0; i < 2; ++i)
    #pragma unroll
    for (int j = 0; j < 4; ++j) acc[i][j] = 0.f;

  #pragma unroll 4
  for (int kk = 0; kk < 64; ++kk) {
    const float2 a = *(const float2*)&As[kk][r2];
    const float4 w4 = *(const float4*)&Ws[kk][cg];
    const float av[2] = {a.x, a.y};
    const float wv[4] = {w4.x, w4.y, w4.z, w4.w};
    #pragma unroll
    for (int ri = 0; ri < 2; ++ri)
      #pragma unroll
      for (int ci = 0; ci < 4; ++ci)
        acc[ri][ci] = fmaf(av[ri], wv[ci], acc[ri][ci]);
  }

  float vv[2][4];
  #pragma unroll
  for (int ri = 0; ri < 2; ++ri) {
    const int row = rowbase + r2 + ri;
    #pragma unroll
    for (int j = 0; j < 4; ++j) {
      const int c = cg + j;
      vv[ri][j] = acc[ri][j] + bo[c] + xin[(size_t)row * CC + c];
      out[(size_t)row * CC + c] = vv[ri][j];
    }
  }
  #pragma unroll
  for (int j = 0; j < 4; ++j) {
    float sp = vv[0][j] + vv[1][j];
    float sq = vv[0][j] * vv[0][j] + vv[1][j] * vv[1][j];
    #pragma unroll
    for (int off = 8; off; off >>= 1) {
      sp += __shfl_down(sp, off);
      sq += __shfl_down(sq, off);
    }
    if ((tid & 15) == 0) {
      s2sum[(size_t)blockIdx.x * CC + cg + j] = sp;
      s2sq[(size_t)blockIdx.x * CC + cg + j] = sq;
    }
  }
}

// ---------------------------------------------------------------------------
// Fused MLP with inline BN2 + BN3 partials (R24 verbatim).
__global__ __launch_bounds__(256) void mlp_k(
    const float* __restrict__ pre2, const float* __restrict__ s2sum,
    const float* __restrict__ s2sq, const float* __restrict__ g2,
    const float* __restrict__ b2, const float* __restrict__ W1,
    const float* __restrict__ b1, const float* __restrict__ W2,
    const float* __restrict__ b2m, float* __restrict__ out,
    float* __restrict__ s3sum, float* __restrict__ s3sq)
{
  __shared__ __align__(16) float As[64][36];
  __shared__ __align__(16) float Wbuf[8704];
  __shared__ __align__(16) float Ts[128][36];
  __shared__ float redp[4][64], redq[4][64];
  __shared__ float sc2[64], sh2[64];

  const int tid = threadIdx.x;
  const int rowbase = blockIdx.x * 32;
  const int bb = blockIdx.x >> 7;
  const int r2 = (tid & 15) * 2;
  const int cg8 = (tid >> 4) * 8;
  const int cg4 = (tid >> 4) * 4;

  {
    const int c = tid & 63, part = tid >> 6;
    float sp = 0.f, sq = 0.f;
    const int b0 = bb * 128 + part * 32;
    for (int k = 0; k < 32; ++k) {
      sp += s2sum[(size_t)(b0 + k) * CC + c];
      sq += s2sq[(size_t)(b0 + k) * CC + c];
    }
    redp[part][c] = sp;
    redq[part][c] = sq;
  }
  __syncthreads();
  if (tid < 64) {
    const int c = tid;
    const float ts = redp[0][c] + redp[1][c] + redp[2][c] + redp[3][c];
    const float tq = redq[0][c] + redq[1][c] + redq[2][c] + redq[3][c];
    const float mean = ts * (1.f / NN);
    const float var = tq * (1.f / NN) - mean * mean;
    const float rstd = rsqrtf(var + 1e-5f);
    sc2[c] = g2[c] * rstd;
    sh2[c] = b2[c] - mean * sc2[c];
  }
  #pragma unroll
  for (int i = 0; i < 32; ++i) {
    int idx = tid + i * 256;
    int c2 = idx >> 6, kk = idx & 63;
    Wbuf[kk * 132 + c2] = W1[(size_t)c2 * 64 + kk];
  }
  __syncthreads();
  #pragma unroll
  for (int i = 0; i < 8; ++i) {
    int idx = tid + i * 256;
    int r = idx >> 6, kk = idx & 63;
    As[kk][r] = pre2[(size_t)(rowbase + r) * CC + kk] * sc2[kk] + sh2[kk];
  }
  __syncthreads();

  float acc1[2][8];
  #pragma unroll
  for (int i = 0; i < 2; ++i)
    #pragma unroll
    for (int j = 0; j < 8; ++j) acc1[i][j] = 0.f;

  #pragma unroll 4
  for (int kk = 0; kk < 64; ++kk) {
    const float2 a = *(const float2*)&As[kk][r2];
    const float av[2] = {a.x, a.y};
    #pragma unroll
    for (int cj = 0; cj < 2; ++cj) {
      const float4 w4 = *(const float4*)&Wbuf[kk * 132 + cg8 + cj * 4];
      const float wv[4] = {w4.x, w4.y, w4.z, w4.w};
      #pragma unroll
      for (int ri = 0; ri < 2; ++ri)
        #pragma unroll
        for (int ci = 0; ci < 4; ++ci)
          acc1[ri][cj * 4 + ci] = fmaf(av[ri], wv[ci], acc1[ri][cj * 4 + ci]);
    }
  }
  #pragma unroll
  for (int ri = 0; ri < 2; ++ri)
    #pragma unroll
    for (int j = 0; j < 8; ++j)
      Ts[cg8 + j][r2 + ri] = fmaxf(acc1[ri][j] + b1[cg8 + j], 0.f);
  __syncthreads();

  #pragma unroll
  for (int i = 0; i < 32; ++i) {
    int idx = tid + i * 256;
    int c2 = idx >> 7, kk = idx & 127;
    Wbuf[kk * 68 + c2] = W2[(size_t)c2 * 128 + kk];
  }
  __syncthreads();

  float acc2[2][4];
  #pragma unroll
  for (int i = 0; i < 2; ++i)
    #pragma unroll
    for (int j = 0; j < 4; ++j) acc2[i][j] = 0.f;

  #pragma unroll 4
  for (int kk = 0; kk < 128; ++kk) {
    const float2 a = *(const float2*)&Ts[kk][r2];
    const float4 w4 = *(const float4*)&Wbuf[kk * 68 + cg4];
    const float av[2] = {a.x, a.y};
    const float wv[4] = {w4.x, w4.y, w4.z, w4.w};
    #pragma unroll
    for (int ri = 0; ri < 2; ++ri)
      #pragma unroll
      for (int ci = 0; ci < 4; ++ci)
        acc2[ri][ci] = fmaf(av[ri], wv[ci], acc2[ri][ci]);
  }

  float vv[2][4];
  #pragma unroll
  for (int ri = 0; ri < 2; ++ri) {
    const int row = rowbase + r2 + ri;
    #pragma unroll
    for (int j = 0; j < 4; ++j) {
      const int c = cg4 + j;
      vv[ri][j] = acc2[ri][j] + b2m[c] + As[c][r2 + ri];
      out[(size_t)row * CC + c] = vv[ri][j];
    }
  }
  #pragma unroll
  for (int j = 0; j < 4; ++j) {
    float sp = vv[0][j] + vv[1][j];
    float sq = vv[0][j] * vv[0][j] + vv[1][j] * vv[1][j];
    #pragma unroll
    for (int off = 8; off; off >>= 1) {
      sp += __shfl_down(sp, off);
      sq += __shfl_down(sq, off);
    }
    if ((tid & 15) == 0) {
      s3sum[(size_t)blockIdx.x * CC + cg4 + j] = sp;
      s3sq[(size_t)blockIdx.x * CC + cg4 + j] = sq;
    }
  }
}

// ---------------------------------------------------------------------------
// Final BN + tanh (R24 verbatim).
__global__ __launch_bounds__(1024) void bn_tanh_k(
    const float* __restrict__ in, const float* __restrict__ s3sum,
    const float* __restrict__ s3sq, const float* __restrict__ g,
    const float* __restrict__ b, float* __restrict__ out)
{
  const int bb = blockIdx.x >> 4;
  const int c4 = (blockIdx.x & 15) * 4;
  const int tid = threadIdx.x;

  __shared__ float tp[8][4], tq[8][4];
  __shared__ float scl[4], shf[4];
  if (tid < 32) {
    const int j = tid & 3, chunk = tid >> 2;
    float sp = 0.f, sq = 0.f;
    const int b0 = bb * 128 + chunk * 16;
    for (int k = 0; k < 16; ++k) {
      sp += s3sum[(size_t)(b0 + k) * CC + c4 + j];
      sq += s3sq[(size_t)(b0 + k) * CC + c4 + j];
    }
    tp[chunk][j] = sp;
    tq[chunk][j] = sq;
  }
  __syncthreads();
  if (tid < 4) {
    const int j = tid;
    float ts = 0.f, tqv = 0.f;
    #pragma unroll
    for (int k = 0; k < 8; ++k) { ts += tp[k][j]; tqv += tq[k][j]; }
    const float mean = ts * (1.f / NN);
    const float var = tqv * (1.f / NN) - mean * mean;
    const float rstd = rsqrtf(var + 1e-5f);
    scl[j] = g[c4 + j] * rstd;
    shf[j] = b[c4 + j] - mean * scl[j];
  }
  __syncthreads();

  const float s0 = scl[0], s1 = scl[1], s2 = scl[2], s3 = scl[3];
  const float h0 = shf[0], h1 = shf[1], h2 = shf[2], h3 = shf[3];
  const float* __restrict__ base = in + (size_t)bb * NN * CC + c4;
  float* __restrict__ ob = out + (size_t)bb * NN * CC + c4;
  #pragma unroll
  for (int i = 0; i < 4; ++i) {
    const size_t idx = (size_t)(tid + i * 1024) * CC;
    const float4 v = *(const float4*)&base[idx];
    float4 o;
    o.x = fast_tanh(v.x * s0 + h0);
    o.y = fast_tanh(v.y * s1 + h1);
    o.z = fast_tanh(v.z * s2 + h2);
    o.w = fast_tanh(v.w * s3 + h3);
    *(float4*)&ob[idx] = o;
  }
}

// ---------------------------------------------------------------------------
extern "C" void kernel_launch(void* const* d_in, const int* in_sizes, int n_in,
                              void* d_out, int out_size, void* d_ws, size_t ws_size,
                              hipStream_t stream)
{
  const float* inp  = (const float*)d_in[0];
  const float* Wp   = (const float*)d_in[2];
  const float* bp   = (const float*)d_in[3];
  const float* Wqkv = (const float*)d_in[4];
  const float* bqkv = (const float*)d_in[5];
  const float* Wo   = (const float*)d_in[6];
  const float* bo   = (const float*)d_in[7];
  const float* g2   = (const float*)d_in[8];
  const float* b2   = (const float*)d_in[9];
  const float* W1   = (const float*)d_in[10];
  const float* b1   = (const float*)d_in[11];
  const float* W2   = (const float*)d_in[12];
  const float* b2m  = (const float*)d_in[13];
  const float* g3   = (const float*)d_in[14];
  const float* b3   = (const float*)d_in[15];

  float* w = (float*)d_ws;
  float* x     = w;                 // [16384][64]
  float* qkvA  = w + 1048576;       // f16 arena: q, k, vt
  float* pre2  = w + 2621440;       // raw pre-BN2 [16384][64]
  float* pre3  = w + 3670016;       // raw pre-BN3 [16384][64]
  float* poW   = w + 4718592;       // f16 attn partial O
  float* rsW   = w + 6815744;       // f16 attn partial rowsums
  float* s2s   = w + 7000064;       // BN2 partial sums   [512][64]
  float* s2q   = w + 7032832;       // BN2 partial sumsq  [512][64]
  float* s3s   = w + 7065600;       // BN3 partial sums   [512][64]
  float* s3q   = w + 7098368;       // BN3 partial sumsq  [512][64]

  _Float16* f16b  = (_Float16*)qkvA;
  _Float16* po16  = (_Float16*)poW;
  _Float16* rs16  = (_Float16*)rsW;

  proj_qkv_k<<<dim3(256), dim3(256), 0, stream>>>(inp, Wp, bp, Wqkv, bqkv, x, f16b);
  attn_k<<<dim3(2048), dim3(256), 0, stream>>>(f16b, f16b + 1048576,
                                               f16b + 2097152, po16, rs16);
  wo_red_k<<<dim3(512), dim3(256), 0, stream>>>(po16, rs16, Wo, bo, x, pre2,
                                                s2s, s2q);
  mlp_k<<<dim3(512), dim3(256), 0, stream>>>(pre2, s2s, s2q, g2, b2,
                                             W1, b1, W2, b2m, pre3, s3s, s3q);
  bn_tanh_k<<<dim3(64), dim3(1024), 0, stream>>>(pre3, s3s, s3q, g3, b3,
                                                 (float*)d_out);
}

// Round 26
// 102.573 us; speedup vs baseline: 1.2285x; 1.2285x over previous
//
#include <hip/hip_runtime.h>
#include <hip/hip_bf16.h>

constexpr int NN = 4096;   // nodes
constexpr int CC = 64;     // channels
constexpr int NH = 4;      // heads
constexpr int DH = 16;     // head dim
constexpr int KSPLIT = 4;  // attention K-dimension split (exact partial sums)

typedef _Float16 f16x4 __attribute__((ext_vector_type(4)));
typedef float f32x4 __attribute__((ext_vector_type(4)));

#define QSCALE 0.36067376022224085f  // 0.25 * log2(e)
#define L2E2   2.8853900817779268f   // 2 * log2(e), for tanh

#if defined(__has_builtin)
#if __has_builtin(__builtin_amdgcn_exp2f)
#define FAST_EXP2(x) __builtin_amdgcn_exp2f(x)
#endif
#if __has_builtin(__builtin_amdgcn_rcpf)
#define FAST_RCP(x) __builtin_amdgcn_rcpf(x)
#endif
#endif
#ifndef FAST_EXP2
#define FAST_EXP2(x) exp2f(x)
#endif
#ifndef FAST_RCP
#define FAST_RCP(x) (1.0f / (x))
#endif

__device__ __forceinline__ float fast_tanh(float x) {
  const float t = FAST_EXP2(x * L2E2);
  return fmaf(-2.f, FAST_RCP(t + 1.f), 1.f);
}

// ---------------------------------------------------------------------------
// Fused project + QKV (R24 verbatim).
__global__ __launch_bounds__(256) void proj_qkv_k(
    const float* __restrict__ inp, const float* __restrict__ Wp,
    const float* __restrict__ bp, const float* __restrict__ Wqkv,
    const float* __restrict__ bqkv, float* __restrict__ xout,
    _Float16* __restrict__ f16b)
{
  __shared__ __align__(16) float As[64][68];
  __shared__ __align__(16) float Xs[64][68];
  __shared__ __align__(16) float W2s[64][196];

  const int tid = threadIdx.x;
  const int rowbase = blockIdx.x * 64;
  const int r4 = (tid & 15) * 4;
  const int cg = (tid >> 4) * 4;
  const int cg2 = (tid >> 4) * 12;

  float acc[4][4];
  #pragma unroll
  for (int i = 0; i < 4; ++i)
    #pragma unroll
    for (int j = 0; j < 4; ++j) acc[i][j] = 0.f;

  for (int k0 = 0; k0 < 128; k0 += 64) {
    if (k0) __syncthreads();
    #pragma unroll
    for (int i = 0; i < 16; ++i) {
      int idx = tid + i * 256;
      int c2 = idx >> 6, kk = idx & 63;
      Xs[kk][c2] = Wp[(size_t)c2 * 128 + k0 + kk];
    }
    #pragma unroll
    for (int i = 0; i < 16; ++i) {
      int idx = tid + i * 256;
      int r = idx >> 6, kk = idx & 63;
      As[kk][r] = inp[(size_t)(rowbase + r) * 128 + k0 + kk];
    }
    __syncthreads();
    #pragma unroll 4
    for (int kk = 0; kk < 64; ++kk) {
      const float4 a = *(const float4*)&As[kk][r4];
      const float4 w4 = *(const float4*)&Xs[kk][cg];
      const float av[4] = {a.x, a.y, a.z, a.w};
      const float wv[4] = {w4.x, w4.y, w4.z, w4.w};
      #pragma unroll
      for (int ri = 0; ri < 4; ++ri)
        #pragma unroll
        for (int ci = 0; ci < 4; ++ci)
          acc[ri][ci] = fmaf(av[ri], wv[ci], acc[ri][ci]);
    }
  }

  float xv[4][4];
  #pragma unroll
  for (int ri = 0; ri < 4; ++ri)
    #pragma unroll
    for (int j = 0; j < 4; ++j) {
      xv[ri][j] = acc[ri][j] + bp[cg + j];
      xout[(size_t)(rowbase + r4 + ri) * CC + cg + j] = xv[ri][j];
    }

  __syncthreads();
  #pragma unroll
  for (int ri = 0; ri < 4; ++ri)
    #pragma unroll
    for (int j = 0; j < 4; ++j)
      Xs[cg + j][r4 + ri] = xv[ri][j];
  #pragma unroll
  for (int i = 0; i < 48; ++i) {
    int idx = tid + i * 256;
    int c2 = idx >> 6, kk = idx & 63;
    W2s[kk][c2] = Wqkv[(size_t)c2 * 64 + kk];
  }
  __syncthreads();

  float acc2[4][12];
  #pragma unroll
  for (int i = 0; i < 4; ++i)
    #pragma unroll
    for (int j = 0; j < 12; ++j) acc2[i][j] = 0.f;

  #pragma unroll 4
  for (int kk = 0; kk < 64; ++kk) {
    const float4 a = *(const float4*)&Xs[kk][r4];
    const float av[4] = {a.x, a.y, a.z, a.w};
    #pragma unroll
    for (int cj = 0; cj < 3; ++cj) {
      const float4 w4 = *(const float4*)&W2s[kk][cg2 + cj * 4];
      const float wv[4] = {w4.x, w4.y, w4.z, w4.w};
      #pragma unroll
      for (int ri = 0; ri < 4; ++ri)
        #pragma unroll
        for (int ci = 0; ci < 4; ++ci)
          acc2[ri][cj * 4 + ci] = fmaf(av[ri], wv[ci], acc2[ri][cj * 4 + ci]);
    }
  }

  #pragma unroll
  for (int ri = 0; ri < 4; ++ri) {
    const int row = rowbase + r4 + ri;
    const int n = row & (NN - 1);
    const int bq = (row >> 12) * NH;
    #pragma unroll
    for (int j = 0; j < 12; ++j) {
      float v = acc2[ri][j] + bqkv[cg2 + j];
      const int c2 = cg2 + j;
      const int which = c2 >> 6;         // 0=q 1=k 2=v
      const int hc = c2 & 63;
      const int bh = bq + (hc >> 4);
      const int d = hc & 15;
      if (which == 0) v *= QSCALE;
      if (which < 2)
        f16b[(size_t)which * 1048576 + ((size_t)bh * NN + n) * DH + d] = (_Float16)v;
      else
        f16b[2097152 + ((size_t)bh * DH + d) * NN + n] = (_Float16)v;
    }
  }
}

// ---------------------------------------------------------------------------
// MFMA flash attention (R21/R24 verbatim: KVB=64, f16 partials, register
// prefetch — measured best).
__global__ __launch_bounds__(256, 6) void attn_k(
    const _Float16* __restrict__ qb, const _Float16* __restrict__ kb,
    const _Float16* __restrict__ vtb, _Float16* __restrict__ po,
    _Float16* __restrict__ rs)
{
  __shared__ _Float16 Kl[64][20];
  __shared__ _Float16 Vl[16][72];

  const int bid = blockIdx.x;
  const int xcd = bid & 7;
  const int rest = bid >> 3;
  const int bh = 2 * xcd + (rest & 1);
  const int ks = (rest >> 1) & 3;
  const int n0 = (rest >> 3) * 128;
  const int tid = threadIdx.x;
  const int w = tid >> 6;
  const int l = tid & 63;
  const int g = l >> 4, i = l & 15;
  const int qbase = n0 + w * 32;
  const int kbeg = ks * (NN / KSPLIT);

  const _Float16* __restrict__ qhp = qb + (size_t)bh * NN * DH;
  const _Float16* __restrict__ khp = kb + (size_t)bh * NN * DH;
  const _Float16* __restrict__ vhp = vtb + (size_t)bh * DH * NN;

  const f16x4 qfA = *(const f16x4*)(qhp + (size_t)(qbase + i) * DH + 4 * g);
  const f16x4 qfB = *(const f16x4*)(qhp + (size_t)(qbase + 16 + i) * DH + 4 * g);

  f32x4 oA = {0.f, 0.f, 0.f, 0.f}, oB = {0.f, 0.f, 0.f, 0.f};
  const f32x4 zz = {0.f, 0.f, 0.f, 0.f};
  float rsA = 0.f, rsB = 0.f;

  const int srow = tid >> 2, spart = (tid & 3) * 4;
  const int sd = tid >> 4, scol = (tid & 15) * 4;

  f16x4 kr = *(const f16x4*)(khp + (size_t)(kbeg + srow) * DH + spart);
  f16x4 vr = *(const f16x4*)(vhp + (size_t)sd * NN + kbeg + scol);

  constexpr int NCH = (NN / KSPLIT) / 64;  // 16
  for (int c = 0; c < NCH; ++c) {
    *(f16x4*)&Kl[srow][spart] = kr;
    *(f16x4*)&Vl[sd][scol] = vr;
    __syncthreads();
    if (c + 1 < NCH) {
      const int nx = kbeg + (c + 1) * 64;
      kr = *(const f16x4*)(khp + (size_t)(nx + srow) * DH + spart);
      vr = *(const f16x4*)(vhp + (size_t)sd * NN + nx + scol);
    }

    #pragma unroll
    for (int kk = 0; kk < 64; kk += 16) {
      const f16x4 kf = *(const f16x4*)&Kl[kk + i][4 * g];
      const f16x4 vf = *(const f16x4*)&Vl[i][kk + 4 * g];
      f32x4 sA = __builtin_amdgcn_mfma_f32_16x16x16f16(kf, qfA, zz, 0, 0, 0);
      f32x4 sB = __builtin_amdgcn_mfma_f32_16x16x16f16(kf, qfB, zz, 0, 0, 0);
      const float a0 = FAST_EXP2(sA[0]), a1 = FAST_EXP2(sA[1]),
                  a2 = FAST_EXP2(sA[2]), a3 = FAST_EXP2(sA[3]);
      const float b0 = FAST_EXP2(sB[0]), b1 = FAST_EXP2(sB[1]),
                  b2 = FAST_EXP2(sB[2]), b3 = FAST_EXP2(sB[3]);
      rsA += (a0 + a1) + (a2 + a3);
      rsB += (b0 + b1) + (b2 + b3);
      const auto alo = __builtin_amdgcn_cvt_pkrtz(a0, a1);
      const auto ahi = __builtin_amdgcn_cvt_pkrtz(a2, a3);
      const auto blo = __builtin_amdgcn_cvt_pkrtz(b0, b1);
      const auto bhi = __builtin_amdgcn_cvt_pkrtz(b2, b3);
      f16x4 pA, pB;
      pA[0] = (_Float16)alo[0]; pA[1] = (_Float16)alo[1];
      pA[2] = (_Float16)ahi[0]; pA[3] = (_Float16)ahi[1];
      pB[0] = (_Float16)blo[0]; pB[1] = (_Float16)blo[1];
      pB[2] = (_Float16)bhi[0]; pB[3] = (_Float16)bhi[1];
      oA = __builtin_amdgcn_mfma_f32_16x16x16f16(pA, vf, oA, 0, 0, 0);
      oB = __builtin_amdgcn_mfma_f32_16x16x16f16(pB, vf, oB, 0, 0, 0);
    }
    __syncthreads();
  }

  rsA += __shfl_xor(rsA, 16); rsA += __shfl_xor(rsA, 32);
  rsB += __shfl_xor(rsB, 16); rsB += __shfl_xor(rsB, 32);

  _Float16* __restrict__ pob = po + (size_t)(ks * 16 + bh) * NN * DH;
  #pragma unroll
  for (int r = 0; r < 4; ++r) {
    const int ql = 4 * g + r;
    pob[(size_t)(qbase + ql) * DH + i] = (_Float16)oA[r];
    pob[(size_t)(qbase + 16 + ql) * DH + i] = (_Float16)oB[r];
  }
  if (g == 0) {
    _Float16* __restrict__ rsb = rs + (size_t)(ks * 16 + bh) * NN;
    rsb[qbase + i] = (_Float16)rsA;
    rsb[qbase + 16 + i] = (_Float16)rsB;
  }
}

// ---------------------------------------------------------------------------
// Wo GEMM + K-split reduce + residual + BN2 partials (R24 verbatim).
__global__ __launch_bounds__(256) void wo_red_k(
    const _Float16* __restrict__ po, const _Float16* __restrict__ rs,
    const float* __restrict__ Wo, const float* __restrict__ bo,
    const float* __restrict__ xin, float* __restrict__ out,
    float* __restrict__ s2sum, float* __restrict__ s2sq)
{
  __shared__ __align__(16) float As[64][36];
  __shared__ __align__(16) float Ws[64][68];
  __shared__ float Linv[32][4];

  const int tid = threadIdx.x;
  const int rowbase = blockIdx.x * 32;
  const int r2 = (tid & 15) * 2;
  const int cg = (tid >> 4) * 4;

  if (tid < 128) {
    const int r = tid & 31, hb = tid >> 5;
    const int row = rowbase + r;
    const int bh = (row >> 12) * NH + hb;
    const int n = row & (NN - 1);
    const size_t rb = (size_t)bh * NN + n;
    const float s = (float)rs[rb] + (float)rs[rb + 65536] +
                    (float)rs[rb + 131072] + (float)rs[rb + 196608];
    Linv[r][hb] = 1.f / s;
  }
  #pragma unroll
  for (int i = 0; i < 16; ++i) {
    int idx = tid + i * 256;
    int c2 = idx >> 6, kk = idx & 63;
    Ws[kk][c2] = Wo[(size_t)c2 * 64 + kk];
  }
  __syncthreads();
  #pragma unroll
  for (int i = 0; i < 8; ++i) {
    int idx = tid + i * 256;
    int r = idx >> 6, kk = idx & 63;
    const int row = rowbase + r;
    const int bh = (row >> 12) * NH + (kk >> 4);
    const int n = row & (NN - 1);
    const int d = kk & 15;
    const size_t base = (((size_t)bh * NN + n) * DH) + d;
    const float v = (float)po[base] + (float)po[base + 1048576] +
                    (float)po[base + 2097152] + (float)po[base + 3145728];
    As[kk][r] = v * Linv[r][kk >> 4];
  }
  __syncthreads();

  float acc[2][4];
  #pragma unroll
  for (int i = 0; i < 2; ++i)
    #pragma unroll
    for (int j = 0; j < 4; ++j) acc[i][j] = 0.f;

  #pragma unroll 4
  for (int kk = 0; kk < 64; ++kk) {
    const float2 a = *(const float2*)&As[kk][r2];
    const float4 w4 = *(const float4*)&Ws[kk][cg];
    const float av[2] = {a.x, a.y};
    const float wv[4] = {w4.x, w4.y, w4.z, w4.w};
    #pragma unroll
    for (int ri = 0; ri < 2; ++ri)
      #pragma unroll
      for (int ci = 0; ci < 4; ++ci)
        acc[ri][ci] = fmaf(av[ri], wv[ci], acc[ri][ci]);
  }

  float vv[2][4];
  #pragma unroll
  for (int ri = 0; ri < 2; ++ri) {
    const int row = rowbase + r2 + ri;
    #pragma unroll
    for (int j = 0; j < 4; ++j) {
      const int c = cg + j;
      vv[ri][j] = acc[ri][j] + bo[c] + xin[(size_t)row * CC + c];
      out[(size_t)row * CC + c] = vv[ri][j];
    }
  }
  #pragma unroll
  for (int j = 0; j < 4; ++j) {
    float sp = vv[0][j] + vv[1][j];
    float sq = vv[0][j] * vv[0][j] + vv[1][j] * vv[1][j];
    #pragma unroll
    for (int off = 8; off; off >>= 1) {
      sp += __shfl_down(sp, off);
      sq += __shfl_down(sq, off);
    }
    if ((tid & 15) == 0) {
      s2sum[(size_t)blockIdx.x * CC + cg + j] = sp;
      s2sq[(size_t)blockIdx.x * CC + cg + j] = sq;
    }
  }
}

// ---------------------------------------------------------------------------
// Fused MLP with inline BN2 + BN3 partials (R24 verbatim).
__global__ __launch_bounds__(256) void mlp_k(
    const float* __restrict__ pre2, const float* __restrict__ s2sum,
    const float* __restrict__ s2sq, const float* __restrict__ g2,
    const float* __restrict__ b2, const float* __restrict__ W1,
    const float* __restrict__ b1, const float* __restrict__ W2,
    const float* __restrict__ b2m, float* __restrict__ out,
    float* __restrict__ s3sum, float* __restrict__ s3sq)
{
  __shared__ __align__(16) float As[64][36];
  __shared__ __align__(16) float Wbuf[8704];
  __shared__ __align__(16) float Ts[128][36];
  __shared__ float redp[4][64], redq[4][64];
  __shared__ float sc2[64], sh2[64];

  const int tid = threadIdx.x;
  const int rowbase = blockIdx.x * 32;
  const int bb = blockIdx.x >> 7;
  const int r2 = (tid & 15) * 2;
  const int cg8 = (tid >> 4) * 8;
  const int cg4 = (tid >> 4) * 4;

  {
    const int c = tid & 63, part = tid >> 6;
    float sp = 0.f, sq = 0.f;
    const int b0 = bb * 128 + part * 32;
    for (int k = 0; k < 32; ++k) {
      sp += s2sum[(size_t)(b0 + k) * CC + c];
      sq += s2sq[(size_t)(b0 + k) * CC + c];
    }
    redp[part][c] = sp;
    redq[part][c] = sq;
  }
  __syncthreads();
  if (tid < 64) {
    const int c = tid;
    const float ts = redp[0][c] + redp[1][c] + redp[2][c] + redp[3][c];
    const float tq = redq[0][c] + redq[1][c] + redq[2][c] + redq[3][c];
    const float mean = ts * (1.f / NN);
    const float var = tq * (1.f / NN) - mean * mean;
    const float rstd = rsqrtf(var + 1e-5f);
    sc2[c] = g2[c] * rstd;
    sh2[c] = b2[c] - mean * sc2[c];
  }
  #pragma unroll
  for (int i = 0; i < 32; ++i) {
    int idx = tid + i * 256;
    int c2 = idx >> 6, kk = idx & 63;
    Wbuf[kk * 132 + c2] = W1[(size_t)c2 * 64 + kk];
  }
  __syncthreads();
  #pragma unroll
  for (int i = 0; i < 8; ++i) {
    int idx = tid + i * 256;
    int r = idx >> 6, kk = idx & 63;
    As[kk][r] = pre2[(size_t)(rowbase + r) * CC + kk] * sc2[kk] + sh2[kk];
  }
  __syncthreads();

  float acc1[2][8];
  #pragma unroll
  for (int i = 0; i < 2; ++i)
    #pragma unroll
    for (int j = 0; j < 8; ++j) acc1[i][j] = 0.f;

  #pragma unroll 4
  for (int kk = 0; kk < 64; ++kk) {
    const float2 a = *(const float2*)&As[kk][r2];
    const float av[2] = {a.x, a.y};
    #pragma unroll
    for (int cj = 0; cj < 2; ++cj) {
      const float4 w4 = *(const float4*)&Wbuf[kk * 132 + cg8 + cj * 4];
      const float wv[4] = {w4.x, w4.y, w4.z, w4.w};
      #pragma unroll
      for (int ri = 0; ri < 2; ++ri)
        #pragma unroll
        for (int ci = 0; ci < 4; ++ci)
          acc1[ri][cj * 4 + ci] = fmaf(av[ri], wv[ci], acc1[ri][cj * 4 + ci]);
    }
  }
  #pragma unroll
  for (int ri = 0; ri < 2; ++ri)
    #pragma unroll
    for (int j = 0; j < 8; ++j)
      Ts[cg8 + j][r2 + ri] = fmaxf(acc1[ri][j] + b1[cg8 + j], 0.f);
  __syncthreads();

  #pragma unroll
  for (int i = 0; i < 32; ++i) {
    int idx = tid + i * 256;
    int c2 = idx >> 7, kk = idx & 127;
    Wbuf[kk * 68 + c2] = W2[(size_t)c2 * 128 + kk];
  }
  __syncthreads();

  float acc2[2][4];
  #pragma unroll
  for (int i = 0; i < 2; ++i)
    #pragma unroll
    for (int j = 0; j < 4; ++j) acc2[i][j] = 0.f;

  #pragma unroll 4
  for (int kk = 0; kk < 128; ++kk) {
    const float2 a = *(const float2*)&Ts[kk][r2];
    const float4 w4 = *(const float4*)&Wbuf[kk * 68 + cg4];
    const float av[2] = {a.x, a.y};
    const float wv[4] = {w4.x, w4.y, w4.z, w4.w};
    #pragma unroll
    for (int ri = 0; ri < 2; ++ri)
      #pragma unroll
      for (int ci = 0; ci < 4; ++ci)
        acc2[ri][ci] = fmaf(av[ri], wv[ci], acc2[ri][ci]);
  }

  float vv[2][4];
  #pragma unroll
  for (int ri = 0; ri < 2; ++ri) {
    const int row = rowbase + r2 + ri;
    #pragma unroll
    for (int j = 0; j < 4; ++j) {
      const int c = cg4 + j;
      vv[ri][j] = acc2[ri][j] + b2m[c] + As[c][r2 + ri];
      out[(size_t)row * CC + c] = vv[ri][j];
    }
  }
  #pragma unroll
  for (int j = 0; j < 4; ++j) {
    float sp = vv[0][j] + vv[1][j];
    float sq = vv[0][j] * vv[0][j] + vv[1][j] * vv[1][j];
    #pragma unroll
    for (int off = 8; off; off >>= 1) {
      sp += __shfl_down(sp, off);
      sq += __shfl_down(sq, off);
    }
    if ((tid & 15) == 0) {
      s3sum[(size_t)blockIdx.x * CC + cg4 + j] = sp;
      s3sq[(size_t)blockIdx.x * CC + cg4 + j] = sq;
    }
  }
}

// ---------------------------------------------------------------------------
// Final BN + tanh (R24 verbatim).
__global__ __launch_bounds__(1024) void bn_tanh_k(
    const float* __restrict__ in, const float* __restrict__ s3sum,
    const float* __restrict__ s3sq, const float* __restrict__ g,
    const float* __restrict__ b, float* __restrict__ out)
{
  const int bb = blockIdx.x >> 4;
  const int c4 = (blockIdx.x & 15) * 4;
  const int tid = threadIdx.x;

  __shared__ float tp[8][4], tq[8][4];
  __shared__ float scl[4], shf[4];
  if (tid < 32) {
    const int j = tid & 3, chunk = tid >> 2;
    float sp = 0.f, sq = 0.f;
    const int b0 = bb * 128 + chunk * 16;
    for (int k = 0; k < 16; ++k) {
      sp += s3sum[(size_t)(b0 + k) * CC + c4 + j];
      sq += s3sq[(size_t)(b0 + k) * CC + c4 + j];
    }
    tp[chunk][j] = sp;
    tq[chunk][j] = sq;
  }
  __syncthreads();
  if (tid < 4) {
    const int j = tid;
    float ts = 0.f, tqv = 0.f;
    #pragma unroll
    for (int k = 0; k < 8; ++k) { ts += tp[k][j]; tqv += tq[k][j]; }
    const float mean = ts * (1.f / NN);
    const float var = tqv * (1.f / NN) - mean * mean;
    const float rstd = rsqrtf(var + 1e-5f);
    scl[j] = g[c4 + j] * rstd;
    shf[j] = b[c4 + j] - mean * scl[j];
  }
  __syncthreads();

  const float s0 = scl[0], s1 = scl[1], s2 = scl[2], s3 = scl[3];
  const float h0 = shf[0], h1 = shf[1], h2 = shf[2], h3 = shf[3];
  const float* __restrict__ base = in + (size_t)bb * NN * CC + c4;
  float* __restrict__ ob = out + (size_t)bb * NN * CC + c4;
  #pragma unroll
  for (int i = 0; i < 4; ++i) {
    const size_t idx = (size_t)(tid + i * 1024) * CC;
    const float4 v = *(const float4*)&base[idx];
    float4 o;
    o.x = fast_tanh(v.x * s0 + h0);
    o.y = fast_tanh(v.y * s1 + h1);
    o.z = fast_tanh(v.z * s2 + h2);
    o.w = fast_tanh(v.w * s3 + h3);
    *(float4*)&ob[idx] = o;
  }
}

// ---------------------------------------------------------------------------
extern "C" void kernel_launch(void* const* d_in, const int* in_sizes, int n_in,
                              void* d_out, int out_size, void* d_ws, size_t ws_size,
                              hipStream_t stream)
{
  const float* inp  = (const float*)d_in[0];
  const float* Wp   = (const float*)d_in[2];
  const float* bp   = (const float*)d_in[3];
  const float* Wqkv = (const float*)d_in[4];
  const float* bqkv = (const float*)d_in[5];
  const float* Wo   = (const float*)d_in[6];
  const float* bo   = (const float*)d_in[7];
  const float* g2   = (const float*)d_in[8];
  const float* b2   = (const float*)d_in[9];
  const float* W1   = (const float*)d_in[10];
  const float* b1   = (const float*)d_in[11];
  const float* W2   = (const float*)d_in[12];
  const float* b2m  = (const float*)d_in[13];
  const float* g3   = (const float*)d_in[14];
  const float* b3   = (const float*)d_in[15];

  float* w = (float*)d_ws;
  float* x     = w;                 // [16384][64]
  float* qkvA  = w + 1048576;       // f16 arena: q, k, vt
  float* pre2  = w + 2621440;       // raw pre-BN2 [16384][64]
  float* pre3  = w + 3670016;       // raw pre-BN3 [16384][64]
  float* poW   = w + 4718592;       // f16 attn partial O
  float* rsW   = w + 6815744;       // f16 attn partial rowsums
  float* s2s   = w + 7000064;       // BN2 partial sums   [512][64]
  float* s2q   = w + 7032832;       // BN2 partial sumsq  [512][64]
  float* s3s   = w + 7065600;       // BN3 partial sums   [512][64]
  float* s3q   = w + 7098368;       // BN3 partial sumsq  [512][64]

  _Float16* f16b  = (_Float16*)qkvA;
  _Float16* po16  = (_Float16*)poW;
  _Float16* rs16  = (_Float16*)rsW;

  proj_qkv_k<<<dim3(256), dim3(256), 0, stream>>>(inp, Wp, bp, Wqkv, bqkv, x, f16b);
  attn_k<<<dim3(2048), dim3(256), 0, stream>>>(f16b, f16b + 1048576,
                                               f16b + 2097152, po16, rs16);
  wo_red_k<<<dim3(512), dim3(256), 0, stream>>>(po16, rs16, Wo, bo, x, pre2,
                                                s2s, s2q);
  mlp_k<<<dim3(512), dim3(256), 0, stream>>>(pre2, s2s, s2q, g2, b2,
                                             W1, b1, W2, b2m, pre3, s3s, s3q);
  bn_tanh_k<<<dim3(64), dim3(1024), 0, stream>>>(pre3, s3s, s3q, g3, b3,
                                                 (float*)d_out);
}